// Round 3
// baseline (527.838 us; speedup 1.0000x reference)
//
#include <hip/hip_runtime.h>
#include <math.h>

// Problem constants (match reference)
#define NCURVES   256
#define GPER      64               // NUM_BEZIERS * NUM_SAMPLES = 2*32
#define NUM_G     (NCURVES*GPER)   // 16384
#define IMG_W     256
#define IMG_H     256
#define TILE      16
#define TILES_X   (IMG_W/TILE)     // 16
#define TILES_Y   (IMG_H/TILE)     // 16
#define NTILES    (TILES_X*TILES_Y)
#define REC_F     12               // floats per gaussian record (48 B, float4-aligned)
#define SEGS      16               // depth segments composited in parallel
#define GSEG      (NUM_G/SEGS)     // 1024 gaussians per segment
#define NSUB      (GSEG/256)       // 4 sub-batches of 256 per segment

#define A_MIN     3.0e-6f          // alpha cutoff for tile bbox
#define P_CUT     (-12.6f)         // per-pixel power cutoff (consistent with A_MIN)
#define T_EPS     1.0e-5f          // transmittance early-out (valid per-segment)

// ---------------------------------------------------------------------------
// Kernel 1 (prep): 256 blocks (curve) x 64 threads (gaussian sample).
// Stable depth rank via wave reduction; conic/color/alpha; bezier mean;
// writes 48B record + packed tile bbox at sorted index gi = rank*64 + tid.
// Block 0 also zeroes the per-tile tickets used by the fused combine.
// record = {mx, my, A, B, C, alpha, cr, cg, cb, 0,0,0}
// ---------------------------------------------------------------------------
__global__ __launch_bounds__(GPER)
void prep(const float* __restrict__ ctrl,        // [256][10][2]
          const float* __restrict__ features,    // [256][3]
          const float* __restrict__ cholesky,    // [256][3]
          const float* __restrict__ opacity,     // [256]
          const float* __restrict__ depth,       // [256]
          float*       __restrict__ recs,        // [NUM_G][12]
          unsigned*    __restrict__ bbox,        // [NUM_G]
          int*         __restrict__ ticket)      // [NTILES]
{
    int c   = blockIdx.x;
    int tid = threadIdx.x;          // 0..63 (exactly one wave)

    if (c == 0) {                   // zero combine tickets (ws is poisoned)
        #pragma unroll
        for (int i = tid; i < NTILES; i += GPER) ticket[i] = 0;
    }

    // ---- stable rank (matches stable argsort over 64x-repeated depths)
    float dc = depth[c];
    int r = 0;
    #pragma unroll
    for (int jj = 0; jj < 4; ++jj) {
        int j = tid + jj*64;
        float dj = depth[j];
        r += (dj < dc) || (dj == dc && j < c);
    }
    #pragma unroll
    for (int off = 32; off > 0; off >>= 1) r += __shfl_down(r, off, 64);
    r = __shfl(r, 0, 64);

    // ---- per-curve params (redundant across 64 lanes; L2-hot)
    float c0 = cholesky[3*c+0] + 0.5f;
    float c1 = cholesky[3*c+1];
    float c2 = cholesky[3*c+2] + 0.5f;
    float s00 = c0*c0;
    float s01 = c0*c1;
    float s11 = c1*c1 + c2*c2;
    float inv = 1.0f / (s00*s11 - s01*s01);
    float A  =  s11*inv;
    float Bc = -s01*inv;
    float Cc =  s00*inv;

    float cr = 1.0f/(1.0f + __expf(-features[3*c+0]));
    float cg = 1.0f/(1.0f + __expf(-features[3*c+1]));
    float cb = 1.0f/(1.0f + __expf(-features[3*c+2]));
    float al = 1.0f/(1.0f + __expf(-opacity[c]));

    float cut = fmaxf(2.0f*(__logf(al) - __logf(A_MIN)), 0.0f);
    float rx = sqrtf(cut * s00);
    float ry = sqrtf(cut * s11);

    // ---- bezier sample -> mean
    int k = tid >> 5;               // bezier segment 0/1
    int s = tid & 31;               // sample 0..31
    float t = 0.007f + (float)s * (0.986f/31.0f);
    float u = 1.0f - t;
    float t2=t*t, t3=t2*t, t4=t3*t, t5=t4*t;
    float u2=u*u, u3=u2*u, u4=u3*u, u5=u4*u;
    float w[6] = { u5, 5.0f*t*u4, 10.0f*t2*u3, 10.0f*t3*u2, 5.0f*t4*u, t5 };

    const float* cp = ctrl + c*20;
    float px = 0.0f, py = 0.0f;
    #pragma unroll
    for (int j = 0; j < 6; ++j) {
        int idx = (k*5 + j) % 10;   // seg0: 0..5 ; seg1: 5,6,7,8,9,0
        px += w[j]*cp[2*idx+0];
        py += w[j]*cp[2*idx+1];
    }
    float mx = (tanhf(px)*0.5f + 0.5f) * (float)IMG_W;
    float my = (tanhf(py)*0.5f + 0.5f) * (float)IMG_H;

    int gi = r*GPER + tid;          // depth-sorted gaussian index (stable ties)
    float* o = recs + (size_t)gi*REC_F;
    o[0]=mx; o[1]=my; o[2]=A; o[3]=Bc; o[4]=Cc; o[5]=al;
    o[6]=cr; o[7]=cg; o[8]=cb; o[9]=0.0f; o[10]=0.0f; o[11]=0.0f;

    int tx0 = min(max((int)floorf((mx - rx) * (1.0f/TILE)), 0), TILES_X-1);
    int tx1 = min(max((int)floorf((mx + rx) * (1.0f/TILE)), 0), TILES_X-1);
    int ty0 = min(max((int)floorf((my - ry) * (1.0f/TILE)), 0), TILES_Y-1);
    int ty1 = min(max((int)floorf((my + ry) * (1.0f/TILE)), 0), TILES_Y-1);
    bbox[gi] = (unsigned)tx0 | ((unsigned)ty0<<8) | ((unsigned)tx1<<16) | ((unsigned)ty1<<24);
}

// ---------------------------------------------------------------------------
// Kernel 2: segmented tile renderer + fused combine.
// SEGS*NTILES = 4096 blocks x 256 threads. Block = (tile, segment).
// bbox loads for all NSUB sub-batches are prefetched upfront (independent).
// After writing its (r,g,b,T) partial, the last-arriving segment block for a
// tile (device-scope ticket) composites the SEGS partials front-to-back and
// writes the final pixels (compositing is associative over depth segments).
// ---------------------------------------------------------------------------
__global__ __launch_bounds__(256)
void render_seg(const float*    __restrict__ recs,
                const unsigned* __restrict__ bbox,
                const float*    __restrict__ background,
                float4*         __restrict__ partial,   // [NTILES][SEGS][256]
                int*            __restrict__ ticket,    // [NTILES]
                float*          __restrict__ out)
{
    __shared__ float4   data[256][3];   // compacted gaussian records (12 KB)
    __shared__ unsigned wcnt[4];
    __shared__ int      sflag;

    int tid   = threadIdx.x;
    int seg   = blockIdx.x & (SEGS-1);
    int tile  = blockIdx.x >> 4;        // 0..255
    int tilex = tile & (TILES_X-1);
    int tiley = tile >> 4;
    int X = tilex*TILE + (tid & (TILE-1));
    int Y = tiley*TILE + (tid >> 4);
    float px = (float)X + 0.5f;
    float py = (float)Y + 0.5f;

    int lane = tid & 63;
    int wid  = tid >> 6;
    unsigned long long lmask = (1ull << lane) - 1ull;

    int gbeg = seg * GSEG;

    // ---- prefetch all sub-batch bboxes (independent loads, issued together)
    bool pred[NSUB];
    {
        unsigned bb[NSUB];
        #pragma unroll
        for (int b = 0; b < NSUB; ++b) bb[b] = bbox[gbeg + b*256 + tid];
        #pragma unroll
        for (int b = 0; b < NSUB; ++b) {
            unsigned v = bb[b];
            int tx0 =  v        & 0xff;
            int ty0 = (v >> 8)  & 0xff;
            int tx1 = (v >> 16) & 0xff;
            int ty1 = (v >> 24) & 0xff;
            pred[b] = (tilex >= tx0) & (tilex <= tx1) & (tiley >= ty0) & (tiley <= ty1);
        }
    }

    float T = 1.0f, accr = 0.0f, accg = 0.0f, accb = 0.0f;

    #pragma unroll 1
    for (int b = 0; b < NSUB; ++b) {
        unsigned long long m = __ballot(pred[b] ? 1 : 0);
        if (lane == 0) wcnt[wid] = (unsigned)__popcll(m);

        // barrier #1: publishes wcnt, protects data[] reuse, block early-out.
        int nalive = __syncthreads_count(T > T_EPS);
        if (nalive == 0) break;

        unsigned c0 = wcnt[0], c1 = wcnt[1], c2 = wcnt[2], c3 = wcnt[3];
        int total = (int)(c0 + c1 + c2 + c3);
        if (total) {                    // uniform; empty sub-batch = 1 barrier
            if (pred[b]) {
                unsigned woff = (wid > 0 ? c0 : 0u) + (wid > 1 ? c1 : 0u) + (wid > 2 ? c2 : 0u);
                int slot = (int)(woff + (unsigned)__popcll(m & lmask));
                const float4* rp = (const float4*)(recs + (size_t)(gbeg + b*256 + tid)*REC_F);
                float4 d0 = rp[0], d1 = rp[1], d2 = rp[2];
                data[slot][0] = d0;
                data[slot][1] = d1;
                data[slot][2] = d2;
            }
            __syncthreads();            // barrier #2: data[] visible

            if (T > T_EPS) {
                for (int j = 0; j < total; ++j) {
                    float4 q0 = data[j][0];         // mx, my, A, B
                    float4 q1 = data[j][1];         // C, alpha, cr, cg
                    float  cb_ = data[j][2].x;      // cb
                    float dx = px - q0.x;
                    float dy = py - q0.y;
                    float p  = -0.5f*(q0.z*dx*dx + q1.x*dy*dy) - q0.w*dx*dy;
                    if (p > P_CUT) {
                        float a = q1.y * __expf(p);
                        a = fminf(a, 0.999f);
                        float wgt = a * T;
                        accr += wgt * q1.z;
                        accg += wgt * q1.w;
                        accb += wgt * cb_;
                        T *= (1.0f - a);
                        if (T < T_EPS) break;   // residual within segment < T_EPS
                    }
                }
            }
        }
    }

    // ---- publish partial, then last block per tile combines (device scope)
    partial[((size_t)tile*SEGS + seg)*256 + tid] = make_float4(accr, accg, accb, T);
    __threadfence();                       // release partial writes (agent scope)
    if (tid == 0) {
        int old = atomicAdd(&ticket[tile], 1);   // device-scope by default
        sflag = (old == SEGS - 1);
    }
    __syncthreads();

    if (sflag) {
        __threadfence();                   // acquire other segments' partials
        const float4* basep = partial + (size_t)tile*SEGS*256;
        float r = 0.0f, g = 0.0f, bl = 0.0f, Tt = 1.0f;
        #pragma unroll
        for (int s = 0; s < SEGS; ++s) {
            float4 q = basep[s*256 + tid];
            r  += Tt * q.x;
            g  += Tt * q.y;
            bl += Tt * q.z;
            Tt *= q.w;
        }
        r  = fminf(fmaxf(r  + Tt*background[0], 0.0f), 1.0f);
        g  = fminf(fmaxf(g  + Tt*background[1], 0.0f), 1.0f);
        bl = fminf(fmaxf(bl + Tt*background[2], 0.0f), 1.0f);

        size_t oi = ((size_t)Y*IMG_W + X)*3;
        out[oi+0] = r;
        out[oi+1] = g;
        out[oi+2] = bl;
    }
}

// ---------------------------------------------------------------------------
extern "C" void kernel_launch(void* const* d_in, const int* in_sizes, int n_in,
                              void* d_out, int out_size, void* d_ws, size_t ws_size,
                              hipStream_t stream)
{
    const float* ctrl       = (const float*)d_in[0];  // (256,10,2)
    const float* features   = (const float*)d_in[1];  // (256,3)
    const float* cholesky   = (const float*)d_in[2];  // (256,3)
    const float* opacity    = (const float*)d_in[3];  // (256,1)
    const float* depth      = (const float*)d_in[4];  // (256,1)
    const float* background = (const float*)d_in[5];  // (3,)
    float* out = (float*)d_out;                       // (256,256,3)

    // workspace layout (16B-aligned)
    char* w = (char*)d_ws;
    float*    recs    = (float*)   (w);                         // 786432 B
    unsigned* bboxp   = (unsigned*)(w + 786432);                //  65536 B
    float4*   partial = (float4*)  (w + 786432 + 65536);        // 16 MiB
    int*      ticket  = (int*)     (w + 786432 + 65536 + 16777216); // 1 KB

    prep<<<NCURVES, GPER, 0, stream>>>(ctrl, features, cholesky, opacity, depth,
                                       recs, bboxp, ticket);
    render_seg<<<SEGS*NTILES, 256, 0, stream>>>(recs, bboxp, background,
                                                partial, ticket, out);
}

// Round 4
// 93.417 us; speedup vs baseline: 5.6503x; 5.6503x over previous
//
#include <hip/hip_runtime.h>
#include <math.h>

// Problem constants (match reference)
#define NCURVES   256
#define GPER      64               // NUM_BEZIERS * NUM_SAMPLES = 2*32
#define NUM_G     (NCURVES*GPER)   // 16384
#define IMG_W     256
#define IMG_H     256
#define TILE      16
#define TILES_X   (IMG_W/TILE)     // 16
#define TILES_Y   (IMG_H/TILE)     // 16
#define NTILES    (TILES_X*TILES_Y)
#define REC_F     12               // floats per gaussian record (48 B, float4-aligned)
#define SEGS      16               // depth segments composited in parallel
#define GSEG      (NUM_G/SEGS)     // 1024 gaussians per segment
#define NSUB      (GSEG/256)       // 4 sub-batches of 256 per segment

#define A_MIN     3.0e-6f          // alpha cutoff for tile bbox
#define P_CUT     (-12.6f)         // per-pixel power cutoff (consistent with A_MIN)
#define T_EPS     1.0e-5f          // transmittance early-out (valid per-segment)

// ---------------------------------------------------------------------------
// Kernel 1 (prep): 256 blocks (curve) x 64 threads (gaussian sample).
// Stable depth rank via wave reduction; conic/color/alpha; bezier mean;
// writes 48B record + packed tile bbox at sorted index gi = rank*64 + tid.
// record = {mx, my, A, B, C, alpha, cr, cg, cb, 0,0,0}
// ---------------------------------------------------------------------------
__global__ __launch_bounds__(GPER)
void prep(const float* __restrict__ ctrl,        // [256][10][2]
          const float* __restrict__ features,    // [256][3]
          const float* __restrict__ cholesky,    // [256][3]
          const float* __restrict__ opacity,     // [256]
          const float* __restrict__ depth,       // [256]
          float*       __restrict__ recs,        // [NUM_G][12]
          unsigned*    __restrict__ bbox)        // [NUM_G]
{
    int c   = blockIdx.x;
    int tid = threadIdx.x;          // 0..63 (exactly one wave)

    // ---- stable rank (matches stable argsort over 64x-repeated depths)
    float dc = depth[c];
    int r = 0;
    #pragma unroll
    for (int jj = 0; jj < 4; ++jj) {
        int j = tid + jj*64;
        float dj = depth[j];
        r += (dj < dc) || (dj == dc && j < c);
    }
    #pragma unroll
    for (int off = 32; off > 0; off >>= 1) r += __shfl_down(r, off, 64);
    r = __shfl(r, 0, 64);

    // ---- per-curve params (redundant across 64 lanes; L2-hot)
    float c0 = cholesky[3*c+0] + 0.5f;
    float c1 = cholesky[3*c+1];
    float c2 = cholesky[3*c+2] + 0.5f;
    float s00 = c0*c0;
    float s01 = c0*c1;
    float s11 = c1*c1 + c2*c2;
    float inv = 1.0f / (s00*s11 - s01*s01);
    float A  =  s11*inv;
    float Bc = -s01*inv;
    float Cc =  s00*inv;

    float cr = 1.0f/(1.0f + __expf(-features[3*c+0]));
    float cg = 1.0f/(1.0f + __expf(-features[3*c+1]));
    float cb = 1.0f/(1.0f + __expf(-features[3*c+2]));
    float al = 1.0f/(1.0f + __expf(-opacity[c]));

    float cut = fmaxf(2.0f*(__logf(al) - __logf(A_MIN)), 0.0f);
    float rx = sqrtf(cut * s00);
    float ry = sqrtf(cut * s11);

    // ---- bezier sample -> mean
    int k = tid >> 5;               // bezier segment 0/1
    int s = tid & 31;               // sample 0..31
    float t = 0.007f + (float)s * (0.986f/31.0f);
    float u = 1.0f - t;
    float t2=t*t, t3=t2*t, t4=t3*t, t5=t4*t;
    float u2=u*u, u3=u2*u, u4=u3*u, u5=u4*u;
    float w[6] = { u5, 5.0f*t*u4, 10.0f*t2*u3, 10.0f*t3*u2, 5.0f*t4*u, t5 };

    const float* cp = ctrl + c*20;
    float px = 0.0f, py = 0.0f;
    #pragma unroll
    for (int j = 0; j < 6; ++j) {
        int idx = (k*5 + j) % 10;   // seg0: 0..5 ; seg1: 5,6,7,8,9,0
        px += w[j]*cp[2*idx+0];
        py += w[j]*cp[2*idx+1];
    }
    float mx = (tanhf(px)*0.5f + 0.5f) * (float)IMG_W;
    float my = (tanhf(py)*0.5f + 0.5f) * (float)IMG_H;

    int gi = r*GPER + tid;          // depth-sorted gaussian index (stable ties)
    float* o = recs + (size_t)gi*REC_F;
    o[0]=mx; o[1]=my; o[2]=A; o[3]=Bc; o[4]=Cc; o[5]=al;
    o[6]=cr; o[7]=cg; o[8]=cb; o[9]=0.0f; o[10]=0.0f; o[11]=0.0f;

    int tx0 = min(max((int)floorf((mx - rx) * (1.0f/TILE)), 0), TILES_X-1);
    int tx1 = min(max((int)floorf((mx + rx) * (1.0f/TILE)), 0), TILES_X-1);
    int ty0 = min(max((int)floorf((my - ry) * (1.0f/TILE)), 0), TILES_Y-1);
    int ty1 = min(max((int)floorf((my + ry) * (1.0f/TILE)), 0), TILES_Y-1);
    bbox[gi] = (unsigned)tx0 | ((unsigned)ty0<<8) | ((unsigned)tx1<<16) | ((unsigned)ty1<<24);
}

// ---------------------------------------------------------------------------
// Kernel 2: segmented tile renderer. SEGS*NTILES = 4096 blocks x 256 threads.
// Block = (tile, segment). All NSUB bbox batches prefetched upfront
// (independent loads). Empty sub-batches cost a single barrier. Writes a
// (r,g,b,T) partial per pixel; kernel boundary provides visibility for the
// combine pass (NO device fences here — buffer_wbl2 storms cost 500us, R3).
// ---------------------------------------------------------------------------
__global__ __launch_bounds__(256)
void render_seg(const float*    __restrict__ recs,
                const unsigned* __restrict__ bbox,
                float4*         __restrict__ partial)   // [SEGS][IMG_H*IMG_W]
{
    __shared__ float4   data[256][3];   // compacted gaussian records (12 KB)
    __shared__ unsigned wcnt[4];

    int tid   = threadIdx.x;
    int seg   = blockIdx.x & (SEGS-1);
    int tile  = blockIdx.x >> 4;        // 0..255
    int tilex = tile & (TILES_X-1);
    int tiley = tile >> 4;
    int X = tilex*TILE + (tid & (TILE-1));
    int Y = tiley*TILE + (tid >> 4);
    float px = (float)X + 0.5f;
    float py = (float)Y + 0.5f;

    int lane = tid & 63;
    int wid  = tid >> 6;
    unsigned long long lmask = (1ull << lane) - 1ull;

    int gbeg = seg * GSEG;

    // ---- prefetch all sub-batch bboxes (independent loads, issued together)
    bool pred[NSUB];
    {
        unsigned bb[NSUB];
        #pragma unroll
        for (int b = 0; b < NSUB; ++b) bb[b] = bbox[gbeg + b*256 + tid];
        #pragma unroll
        for (int b = 0; b < NSUB; ++b) {
            unsigned v = bb[b];
            int tx0 =  v        & 0xff;
            int ty0 = (v >> 8)  & 0xff;
            int tx1 = (v >> 16) & 0xff;
            int ty1 = (v >> 24) & 0xff;
            pred[b] = (tilex >= tx0) & (tilex <= tx1) & (tiley >= ty0) & (tiley <= ty1);
        }
    }

    float T = 1.0f, accr = 0.0f, accg = 0.0f, accb = 0.0f;

    #pragma unroll 1
    for (int b = 0; b < NSUB; ++b) {
        unsigned long long m = __ballot(pred[b] ? 1 : 0);
        if (lane == 0) wcnt[wid] = (unsigned)__popcll(m);

        // barrier #1: publishes wcnt, protects data[] reuse, block early-out.
        int nalive = __syncthreads_count(T > T_EPS);
        if (nalive == 0) break;

        unsigned c0 = wcnt[0], c1 = wcnt[1], c2 = wcnt[2], c3 = wcnt[3];
        int total = (int)(c0 + c1 + c2 + c3);
        if (total) {                    // uniform; empty sub-batch = 1 barrier
            if (pred[b]) {
                unsigned woff = (wid > 0 ? c0 : 0u) + (wid > 1 ? c1 : 0u) + (wid > 2 ? c2 : 0u);
                int slot = (int)(woff + (unsigned)__popcll(m & lmask));
                const float4* rp = (const float4*)(recs + (size_t)(gbeg + b*256 + tid)*REC_F);
                float4 d0 = rp[0], d1 = rp[1], d2 = rp[2];
                data[slot][0] = d0;
                data[slot][1] = d1;
                data[slot][2] = d2;
            }
            __syncthreads();            // barrier #2: data[] visible

            if (T > T_EPS) {
                for (int j = 0; j < total; ++j) {
                    float4 q0 = data[j][0];         // mx, my, A, B
                    float4 q1 = data[j][1];         // C, alpha, cr, cg
                    float  cb_ = data[j][2].x;      // cb
                    float dx = px - q0.x;
                    float dy = py - q0.y;
                    float p  = -0.5f*(q0.z*dx*dx + q1.x*dy*dy) - q0.w*dx*dy;
                    if (p > P_CUT) {
                        float a = q1.y * __expf(p);
                        a = fminf(a, 0.999f);
                        float wgt = a * T;
                        accr += wgt * q1.z;
                        accg += wgt * q1.w;
                        accb += wgt * cb_;
                        T *= (1.0f - a);
                        if (T < T_EPS) break;   // residual within segment < T_EPS
                    }
                }
            }
        }
    }

    partial[(size_t)seg*(IMG_W*IMG_H) + (size_t)Y*IMG_W + X] =
        make_float4(accr, accg, accb, T);
}

// ---------------------------------------------------------------------------
// Kernel 3: combine segments front-to-back, add background, clamp, store.
// ---------------------------------------------------------------------------
__global__ __launch_bounds__(256)
void combine(const float4* __restrict__ partial,
             const float*  __restrict__ background,
             float*        __restrict__ out)
{
    int p = blockIdx.x * 256 + threadIdx.x;     // pixel 0..65535

    float accr = 0.0f, accg = 0.0f, accb = 0.0f, T = 1.0f;
    #pragma unroll
    for (int s = 0; s < SEGS; ++s) {
        float4 q = partial[(size_t)s*(IMG_W*IMG_H) + p];
        accr += T * q.x;
        accg += T * q.y;
        accb += T * q.z;
        T    *= q.w;
    }
    float r = fminf(fmaxf(accr + T*background[0], 0.0f), 1.0f);
    float g = fminf(fmaxf(accg + T*background[1], 0.0f), 1.0f);
    float b = fminf(fmaxf(accb + T*background[2], 0.0f), 1.0f);

    size_t oi = (size_t)p*3;
    out[oi+0] = r;
    out[oi+1] = g;
    out[oi+2] = b;
}

// ---------------------------------------------------------------------------
extern "C" void kernel_launch(void* const* d_in, const int* in_sizes, int n_in,
                              void* d_out, int out_size, void* d_ws, size_t ws_size,
                              hipStream_t stream)
{
    const float* ctrl       = (const float*)d_in[0];  // (256,10,2)
    const float* features   = (const float*)d_in[1];  // (256,3)
    const float* cholesky   = (const float*)d_in[2];  // (256,3)
    const float* opacity    = (const float*)d_in[3];  // (256,1)
    const float* depth      = (const float*)d_in[4];  // (256,1)
    const float* background = (const float*)d_in[5];  // (3,)
    float* out = (float*)d_out;                       // (256,256,3)

    // workspace layout (16B-aligned)
    char* w = (char*)d_ws;
    float*    recs    = (float*)   (w);                    // 786432 B
    unsigned* bboxp   = (unsigned*)(w + 786432);           //  65536 B
    float4*   partial = (float4*)  (w + 786432 + 65536);   // 16 MiB

    prep<<<NCURVES, GPER, 0, stream>>>(ctrl, features, cholesky, opacity, depth,
                                       recs, bboxp);
    render_seg<<<SEGS*NTILES, 256, 0, stream>>>(recs, bboxp, partial);
    combine<<<(IMG_W*IMG_H)/256, 256, 0, stream>>>(partial, background, out);
}